// Round 14
// baseline (49.238 us; speedup 1.0000x reference)
//
#include <hip/hip_runtime.h>
#include <hip/hip_fp16.h>
#include <stdint.h>

#define H 1024
#define BATCH 2048
#define KDIM 2048   // input + hidden concatenated (elements)
#define NDIM 4096   // 4 gates
#define EPS 1e-5f

#define BM 128
#define BN 128   // 32 h-columns x 4 interleaved gates
#define BK 256   // i8 elements per K-step (32 KB per matrix tile)

typedef __attribute__((ext_vector_type(4))) int i32x4;
typedef __attribute__((ext_vector_type(16))) int i32x16;

__device__ __forceinline__ float fast_sig(float x) {
  x = fminf(30.f, fmaxf(-30.f, x));
  float e = __expf(x);
  return e / (e + 1.f);
}

__device__ __forceinline__ float fast_tanh(float x) {
  x = fminf(15.f, fmaxf(-15.f, x));
  float e = __expf(2.f * x);
  return (e - 1.f) / (e + 1.f);
}

// ---- quant: per-row max-scale int8; B rows gate-interleaved (h*4+g) --------
__global__ __launch_bounds__(256) void quant_kernel(
    const float* __restrict__ x, const float* __restrict__ h,
    const float* __restrict__ Wih, const float* __restrict__ Whh,
    const float* __restrict__ b_ih, const float* __restrict__ b_hh,
    char* __restrict__ Ai8, char* __restrict__ Bi8,
    float* __restrict__ sA, float* __restrict__ sB, float* __restrict__ bsum) {
  const int r = blockIdx.x;
  const int t = threadIdx.x;
  const float* s0;
  const float* s1;
  char* dst;
  float* sOut;
  float bs = 0.f;
  float* bOut = nullptr;
  if (r < BATCH) {
    s0 = x + (size_t)r * H;
    s1 = h + (size_t)r * H;
    dst = Ai8 + (size_t)r * KDIM;
    sOut = sA + r;
  } else {
    const int rb = r - BATCH;
    const int g = rb >> 10;    // gate 0..3 (i,f,o,g)
    const int hh = rb & 1023;  // h index
    const int rr = hh * 4 + g; // interleaved row
    s0 = Wih + (size_t)rb * H;
    s1 = Whh + (size_t)rb * H;
    dst = Bi8 + (size_t)rr * KDIM;
    sOut = sB + rr;
    bs = b_ih[rb] + b_hh[rb];
    bOut = bsum + rr;
  }
  const float* src = (t < 128) ? (s0 + t * 8) : (s1 + (t - 128) * 8);
  float4 v0 = *(const float4*)src;
  float4 v1 = *(const float4*)(src + 4);
  float vv[8] = {v0.x, v0.y, v0.z, v0.w, v1.x, v1.y, v1.z, v1.w};

  float m = 0.f;
#pragma unroll
  for (int i = 0; i < 8; ++i) m = fmaxf(m, fabsf(vv[i]));
#pragma unroll
  for (int off = 32; off > 0; off >>= 1) m = fmaxf(m, __shfl_xor(m, off));
  __shared__ float red[4];
  if ((t & 63) == 0) red[t >> 6] = m;
  __syncthreads();
  m = fmaxf(fmaxf(red[0], red[1]), fmaxf(red[2], red[3]));
  m = fmaxf(m, 1e-20f);
  if (t == 0) {
    *sOut = m * (1.0f / 127.0f);
    if (bOut) *bOut = bs;
  }
  const float inv = 127.0f / m;

  char out[8];
#pragma unroll
  for (int i = 0; i < 8; ++i) {
    int qi = (int)rintf(vv[i] * inv);
    qi = max(-127, min(127, qi));
    out[i] = (char)qi;
  }
  *(int2*)(dst + t * 8) = *(const int2*)out;
}

// ---- GEMM + fused gate/c-update: i8 MFMA 32x32x32, BK=256, NT=8 ------------
__device__ __forceinline__ void load_lds16(const void* g, void* l) {
  __builtin_amdgcn_global_load_lds(
      (const __attribute__((address_space(1))) void*)g,
      (__attribute__((address_space(3))) void*)l, 16, 0, 0);
}

__global__ __launch_bounds__(256, 2) void gemm_kernel(
    const char* __restrict__ A8,   // 2048 x 2048 i8
    const char* __restrict__ B8,   // 4096 x 2048 i8 (interleaved rows)
    const float* __restrict__ sA, const float* __restrict__ sB,
    const float* __restrict__ bsum, const float* __restrict__ c_in,
    __half* __restrict__ cvg, __half* __restrict__ ovg) {  // 2048 x 1024 each
  __shared__ __align__(16) char smem[66560];  // staging 64KB | pre[128][130] f32
  char* sAt = smem;
  char* sBt = smem + 32768;
  float* pf = (float*)smem;

  const int tid = threadIdx.x;
  const int wave = tid >> 6;
  const int lane = tid & 63;
  const int m0 = blockIdx.y * BM;
  const int n0 = blockIdx.x * BN;
  const int wr = (wave >> 1) * 64;
  const int wc = (wave & 1) * 64;

  const int lrow = lane & 31;   // fragment row/col within 32
  const int khalf = lane >> 5;  // 0..1 -> k offset 16*khalf
  const int rxor = (lrow & 7);

  i32x16 acc[2][2] = {};

  const int NT = KDIM / BK;  // 8

  for (int t = 0; t < NT; ++t) {
    const int k0 = t * BK;
#pragma unroll
    for (int p = 0; p < 8; ++p) {
      const int rg = wave * 32 + p * 4;  // 4-row group base
      const int srcoff = (((lane & 15) ^ ((4 * (p & 1)) + (lane >> 4))) << 4);
      load_lds16(A8 + (size_t)(m0 + rg + (lane >> 4)) * KDIM + k0 + srcoff,
                 sAt + rg * BK);
      load_lds16(B8 + (size_t)(n0 + rg + (lane >> 4)) * KDIM + k0 + srcoff,
                 sBt + rg * BK);
    }
    asm volatile("s_waitcnt vmcnt(0)" ::: "memory");
    __syncthreads();

#pragma unroll
    for (int ks = 0; ks < 8; ++ks) {
      // logical 16B chunk = ks*2 + khalf; phys = logical ^ (row&7)
      const int coff = (((ks * 2 + khalf) ^ rxor) << 4);
      i32x4 a[2], b[2];
#pragma unroll
      for (int i = 0; i < 2; ++i) {
        a[i] = *(const i32x4*)(sAt + (wr + i * 32 + lrow) * BK + coff);
        b[i] = *(const i32x4*)(sBt + (wc + i * 32 + lrow) * BK + coff);
      }
      __builtin_amdgcn_s_setprio(1);
#pragma unroll
      for (int i = 0; i < 2; ++i)
#pragma unroll
        for (int j = 0; j < 2; ++j)
          acc[i][j] =
              __builtin_amdgcn_mfma_i32_32x32x32_i8(a[i], b[j], acc[i][j], 0, 0, 0);
      __builtin_amdgcn_s_setprio(0);
    }

    __syncthreads();
  }

  // dequant + bias -> pre-activation tile in LDS (stride 130 to spread banks)
  // C/D layout (verified m74/m101): col = lane&31, row = (reg&3)+8*(reg>>2)+4*(lane>>5)
#pragma unroll
  for (int i = 0; i < 2; ++i)
#pragma unroll
    for (int j = 0; j < 2; ++j) {
      const int col = wc + j * 32 + lrow;
      const float sb_ = sB[n0 + col];
      const float bb_ = bsum[n0 + col];
#pragma unroll
      for (int r = 0; r < 16; ++r) {
        const int row = wr + i * 32 + (r & 3) + 8 * (r >> 2) + 4 * khalf;
        pf[row * 130 + col] = (float)acc[i][j][r] * sA[m0 + row] * sb_ + bb_;
      }
    }
  __syncthreads();

  // fused gate math: thread -> (row = tid>>1, 16 contiguous h), coalesced IO
  const int mrow = tid >> 1;
  const int hq = tid & 1;
  const size_t obase = (size_t)(m0 + mrow) * H + blockIdx.x * 32 + hq * 16;
  const float* prow = pf + mrow * 130 + hq * 64;

  float4 cin4[4];
#pragma unroll
  for (int q = 0; q < 4; ++q) cin4[q] = *(const float4*)(c_in + obase + q * 4);

  ushort hc[16], ho[16];
#pragma unroll
  for (int k = 0; k < 16; ++k) {
    float4 g4 = *(const float4*)(prow + k * 4);  // i,f,o,g for this (m,h)
    float iv = fast_sig(g4.x);
    float fv = fast_sig(g4.y);
    float ov = fast_sig(g4.z);
    float gv = fast_tanh(g4.w);
    float cv = ((const float*)&cin4[k >> 2])[k & 3] * fv + iv * gv;
    __half hcv = __float2half(cv);
    __half hov = __float2half(ov);
    hc[k] = *(ushort*)&hcv;
    ho[k] = *(ushort*)&hov;
  }
#pragma unroll
  for (int q = 0; q < 2; ++q) {
    *(int4*)(cvg + obase + q * 8) = *(const int4*)&hc[q * 8];
    *(int4*)(ovg + obase + q * 8) = *(const int4*)&ho[q * 8];
  }
}

// ---- LN epilogue: row mean/var over cv, outputs h_t, c_t -------------------
__global__ __launch_bounds__(256) void ln_kernel(
    const __half* __restrict__ cvg, const __half* __restrict__ ovg,
    const float* __restrict__ ln_w, const float* __restrict__ ln_b,
    float* __restrict__ h_out, float* __restrict__ c_out) {
  const int m = blockIdx.x;
  const int t = threadIdx.x;
  const int j = t << 2;
  ushort4 uc = *(const ushort4*)(cvg + (size_t)m * H + j);
  ushort4 uo = *(const ushort4*)(ovg + (size_t)m * H + j);
  float cv[4] = {__half2float(*(__half*)&uc.x), __half2float(*(__half*)&uc.y),
                 __half2float(*(__half*)&uc.z), __half2float(*(__half*)&uc.w)};
  float ov[4] = {__half2float(*(__half*)&uo.x), __half2float(*(__half*)&uo.y),
                 __half2float(*(__half*)&uo.z), __half2float(*(__half*)&uo.w)};

  float s = 0.f, q = 0.f;
#pragma unroll
  for (int r = 0; r < 4; ++r) {
    s += cv[r];
    q += cv[r] * cv[r];
  }
#pragma unroll
  for (int off = 32; off > 0; off >>= 1) {
    s += __shfl_xor(s, off);
    q += __shfl_xor(q, off);
  }
  __shared__ float red[8];
  const int wv = t >> 6, ln = t & 63;
  if (ln == 0) {
    red[wv] = s;
    red[wv + 4] = q;
  }
  __syncthreads();
  s = red[0] + red[1] + red[2] + red[3];
  q = red[4] + red[5] + red[6] + red[7];
  const float mu = s * (1.f / H);
  const float var = q * (1.f / H) - mu * mu;
  const float rstd = rsqrtf(var + EPS);

  float4 lw = *(const float4*)(ln_w + j);
  float4 lb = *(const float4*)(ln_b + j);
  float4 hov, cov;
#pragma unroll
  for (int r = 0; r < 4; ++r) {
    float cn = (cv[r] - mu) * rstd * ((const float*)&lw)[r] + ((const float*)&lb)[r];
    ((float*)&cov)[r] = cn;
    ((float*)&hov)[r] = ov[r] * fast_tanh(cn);
  }
  *(float4*)(h_out + (size_t)m * H + j) = hov;
  *(float4*)(c_out + (size_t)m * H + j) = cov;
}

extern "C" void kernel_launch(void* const* d_in, const int* in_sizes, int n_in,
                              void* d_out, int out_size, void* d_ws, size_t ws_size,
                              hipStream_t stream) {
  const float* x = (const float*)d_in[0];
  const float* h = (const float*)d_in[1];
  const float* c = (const float*)d_in[2];
  const float* Wih = (const float*)d_in[3];
  const float* b_ih = (const float*)d_in[4];
  const float* Whh = (const float*)d_in[5];
  const float* b_hh = (const float*)d_in[6];
  const float* ln_w = (const float*)d_in[7];
  const float* ln_b = (const float*)d_in[8];

  char* Ai8 = (char*)d_ws;                                    // 4 MB @ 0
  char* Bi8 = (char*)d_ws + (4u << 20);                       // 8 MB @ 4M
  float* sA = (float*)((char*)d_ws + (12u << 20));            // 8 KB @ 12M
  float* sB = (float*)((char*)d_ws + (12u << 20) + 32768);    // 16 KB
  float* bsum = (float*)((char*)d_ws + (12u << 20) + 98304);  // 16 KB
  __half* cvg = (__half*)((char*)d_ws + (16u << 20));         // 4 MB @ 16M
  __half* ovg = (__half*)((char*)d_ws + (20u << 20));         // 4 MB @ 20M

  float* h_out = (float*)d_out;
  float* c_out = (float*)d_out + (size_t)BATCH * H;

  quant_kernel<<<BATCH + NDIM, 256, 0, stream>>>(x, h, Wih, Whh, b_ih, b_hh,
                                                 Ai8, Bi8, sA, sB, bsum);
  dim3 g(NDIM / BN, BATCH / BM);
  gemm_kernel<<<g, 256, 0, stream>>>(Ai8, Bi8, sA, sB, bsum, c, cvg, ovg);
  ln_kernel<<<BATCH, 256, 0, stream>>>(cvg, ovg, ln_w, ln_b, h_out, c_out);
}

// Round 15
// 46.739 us; speedup vs baseline: 1.0535x; 1.0535x over previous
//
#include <hip/hip_runtime.h>
#include <hip/hip_fp16.h>
#include <stdint.h>

#define H 1024
#define BATCH 2048
#define KDIM 2048   // input + hidden concatenated (elements)
#define NDIM 4096   // 4 gates
#define EPS 1e-5f

#define BM 128
#define BN 128   // 32 h-columns x 4 interleaved gates
#define BK 256   // i8 elements per K-step (32 KB per matrix tile)

typedef __attribute__((ext_vector_type(4))) int i32x4;

__device__ __forceinline__ float fast_sig(float x) {
  x = fminf(30.f, fmaxf(-30.f, x));
  float e = __expf(x);
  return e / (e + 1.f);
}

__device__ __forceinline__ float fast_tanh(float x) {
  x = fminf(15.f, fmaxf(-15.f, x));
  float e = __expf(2.f * x);
  return (e - 1.f) / (e + 1.f);
}

// ---- quant: per-row max-scale int8; B rows gate-interleaved (h*4+g) --------
__global__ __launch_bounds__(256) void quant_kernel(
    const float* __restrict__ x, const float* __restrict__ h,
    const float* __restrict__ Wih, const float* __restrict__ Whh,
    const float* __restrict__ b_ih, const float* __restrict__ b_hh,
    char* __restrict__ Ai8, char* __restrict__ Bi8,
    float* __restrict__ sA, float* __restrict__ sB, float* __restrict__ bsum) {
  const int r = blockIdx.x;
  const int t = threadIdx.x;
  const float* s0;
  const float* s1;
  char* dst;
  float* sOut;
  float bs = 0.f;
  float* bOut = nullptr;
  if (r < BATCH) {
    s0 = x + (size_t)r * H;
    s1 = h + (size_t)r * H;
    dst = Ai8 + (size_t)r * KDIM;
    sOut = sA + r;
  } else {
    const int rb = r - BATCH;
    const int g = rb >> 10;    // gate 0..3 (i,f,o,g)
    const int hh = rb & 1023;  // h index
    const int rr = hh * 4 + g; // interleaved row
    s0 = Wih + (size_t)rb * H;
    s1 = Whh + (size_t)rb * H;
    dst = Bi8 + (size_t)rr * KDIM;
    sOut = sB + rr;
    bs = b_ih[rb] + b_hh[rb];
    bOut = bsum + rr;
  }
  const float* src = (t < 128) ? (s0 + t * 8) : (s1 + (t - 128) * 8);
  float4 v0 = *(const float4*)src;
  float4 v1 = *(const float4*)(src + 4);
  float vv[8] = {v0.x, v0.y, v0.z, v0.w, v1.x, v1.y, v1.z, v1.w};

  float m = 0.f;
#pragma unroll
  for (int i = 0; i < 8; ++i) m = fmaxf(m, fabsf(vv[i]));
#pragma unroll
  for (int off = 32; off > 0; off >>= 1) m = fmaxf(m, __shfl_xor(m, off));
  __shared__ float red[4];
  if ((t & 63) == 0) red[t >> 6] = m;
  __syncthreads();
  m = fmaxf(fmaxf(red[0], red[1]), fmaxf(red[2], red[3]));
  m = fmaxf(m, 1e-20f);
  if (t == 0) {
    *sOut = m * (1.0f / 127.0f);
    if (bOut) *bOut = bs;
  }
  const float inv = 127.0f / m;

  char out[8];
#pragma unroll
  for (int i = 0; i < 8; ++i) {
    int qi = (int)rintf(vv[i] * inv);
    qi = max(-127, min(127, qi));
    out[i] = (char)qi;
  }
  *(int2*)(dst + t * 8) = *(const int2*)out;
}

// ---- GEMM + fused gate/c-update: int8 MFMA 16x16x64, BK=256, NT=8 ----------
__device__ __forceinline__ void load_lds16(const void* g, void* l) {
  __builtin_amdgcn_global_load_lds(
      (const __attribute__((address_space(1))) void*)g,
      (__attribute__((address_space(3))) void*)l, 16, 0, 0);
}

__global__ __launch_bounds__(256, 2) void gemm_kernel(
    const char* __restrict__ A8,   // 2048 x 2048 i8
    const char* __restrict__ B8,   // 4096 x 2048 i8 (interleaved rows)
    const float* __restrict__ sA, const float* __restrict__ sB,
    const float* __restrict__ bsum, const float* __restrict__ c_in,
    __half* __restrict__ cvg, __half* __restrict__ ovg) {  // 2048 x 1024 each
  __shared__ __align__(16) char smem[66560];  // staging 64KB | pre[128][130] f32
  char* sAt = smem;
  char* sBt = smem + 32768;
  float* pf = (float*)smem;

  const int tid = threadIdx.x;
  const int wave = tid >> 6;
  const int lane = tid & 63;
  const int m0 = blockIdx.y * BM;
  const int n0 = blockIdx.x * BN;
  const int wr = (wave >> 1) * 64;
  const int wc = (wave & 1) * 64;

  const int frow = lane & 15;
  const int klane = lane >> 4;  // 0..3
  const int rxor = (frow & 7);

  i32x4 acc[4][4] = {};

  const int NT = KDIM / BK;  // 8

  for (int t = 0; t < NT; ++t) {
    const int k0 = t * BK;
#pragma unroll
    for (int p = 0; p < 8; ++p) {
      const int rg = wave * 32 + p * 4;  // 4-row group base
      const int srcoff = (((lane & 15) ^ ((4 * (p & 1)) + (lane >> 4))) << 4);
      load_lds16(A8 + (size_t)(m0 + rg + (lane >> 4)) * KDIM + k0 + srcoff,
                 sAt + rg * BK);
      load_lds16(B8 + (size_t)(n0 + rg + (lane >> 4)) * KDIM + k0 + srcoff,
                 sBt + rg * BK);
    }
    asm volatile("s_waitcnt vmcnt(0)" ::: "memory");
    __syncthreads();

#pragma unroll
    for (int ks = 0; ks < 4; ++ks) {
      const int coff = (((ks * 4 + klane) ^ rxor) << 4);
      i32x4 a[4], b[4];
#pragma unroll
      for (int i = 0; i < 4; ++i) {
        a[i] = *(const i32x4*)(sAt + (wr + i * 16 + frow) * BK + coff);
        b[i] = *(const i32x4*)(sBt + (wc + i * 16 + frow) * BK + coff);
      }
      __builtin_amdgcn_s_setprio(1);
#pragma unroll
      for (int i = 0; i < 4; ++i)
#pragma unroll
        for (int j = 0; j < 4; ++j)
          acc[i][j] =
              __builtin_amdgcn_mfma_i32_16x16x64_i8(a[i], b[j], acc[i][j], 0, 0, 0);
      __builtin_amdgcn_s_setprio(0);
    }

    __syncthreads();
  }

  // dequant + bias -> pre-activation tile in LDS (stride 130 to spread banks)
  const int crow = (lane >> 4) << 2;
  const int ccol = lane & 15;
  float scA_[4][4], scB_[4], bs_[4];
#pragma unroll
  for (int j = 0; j < 4; ++j) {
    scB_[j] = sB[n0 + wc + j * 16 + ccol];
    bs_[j] = bsum[n0 + wc + j * 16 + ccol];
  }
#pragma unroll
  for (int i = 0; i < 4; ++i)
#pragma unroll
    for (int r = 0; r < 4; ++r) scA_[i][r] = sA[m0 + wr + i * 16 + crow + r];

#pragma unroll
  for (int i = 0; i < 4; ++i)
#pragma unroll
    for (int j = 0; j < 4; ++j) {
      const int col = wc + j * 16 + ccol;
#pragma unroll
      for (int r = 0; r < 4; ++r)
        pf[(wr + i * 16 + crow + r) * 130 + col] =
            (float)acc[i][j][r] * scA_[i][r] * scB_[j] + bs_[j];
    }
  __syncthreads();

  // fused gate math: thread -> (row = tid>>1, 16 contiguous h), coalesced IO
  const int mrow = tid >> 1;
  const int hq = tid & 1;
  const size_t obase = (size_t)(m0 + mrow) * H + blockIdx.x * 32 + hq * 16;
  const float* prow = pf + mrow * 130 + hq * 64;

  float4 cin4[4];
#pragma unroll
  for (int q = 0; q < 4; ++q) cin4[q] = *(const float4*)(c_in + obase + q * 4);

  ushort hc[16], ho[16];
#pragma unroll
  for (int k = 0; k < 16; ++k) {
    float4 g4 = *(const float4*)(prow + k * 4);  // i,f,o,g for this (m,h)
    float iv = fast_sig(g4.x);
    float fv = fast_sig(g4.y);
    float ov = fast_sig(g4.z);
    float gv = fast_tanh(g4.w);
    float cv = ((const float*)&cin4[k >> 2])[k & 3] * fv + iv * gv;
    __half hcv = __float2half(cv);
    __half hov = __float2half(ov);
    hc[k] = *(ushort*)&hcv;
    ho[k] = *(ushort*)&hov;
  }
#pragma unroll
  for (int q = 0; q < 2; ++q) {
    *(int4*)(cvg + obase + q * 8) = *(const int4*)&hc[q * 8];
    *(int4*)(ovg + obase + q * 8) = *(const int4*)&ho[q * 8];
  }
}

// ---- LN epilogue: row mean/var over cv, outputs h_t, c_t -------------------
__global__ __launch_bounds__(256) void ln_kernel(
    const __half* __restrict__ cvg, const __half* __restrict__ ovg,
    const float* __restrict__ ln_w, const float* __restrict__ ln_b,
    float* __restrict__ h_out, float* __restrict__ c_out) {
  const int m = blockIdx.x;
  const int t = threadIdx.x;
  const int j = t << 2;
  ushort4 uc = *(const ushort4*)(cvg + (size_t)m * H + j);
  ushort4 uo = *(const ushort4*)(ovg + (size_t)m * H + j);
  float cv[4] = {__half2float(*(__half*)&uc.x), __half2float(*(__half*)&uc.y),
                 __half2float(*(__half*)&uc.z), __half2float(*(__half*)&uc.w)};
  float ov[4] = {__half2float(*(__half*)&uo.x), __half2float(*(__half*)&uo.y),
                 __half2float(*(__half*)&uo.z), __half2float(*(__half*)&uo.w)};

  float s = 0.f, q = 0.f;
#pragma unroll
  for (int r = 0; r < 4; ++r) {
    s += cv[r];
    q += cv[r] * cv[r];
  }
#pragma unroll
  for (int off = 32; off > 0; off >>= 1) {
    s += __shfl_xor(s, off);
    q += __shfl_xor(q, off);
  }
  __shared__ float red[8];
  const int wv = t >> 6, ln = t & 63;
  if (ln == 0) {
    red[wv] = s;
    red[wv + 4] = q;
  }
  __syncthreads();
  s = red[0] + red[1] + red[2] + red[3];
  q = red[4] + red[5] + red[6] + red[7];
  const float mu = s * (1.f / H);
  const float var = q * (1.f / H) - mu * mu;
  const float rstd = rsqrtf(var + EPS);

  float4 lw = *(const float4*)(ln_w + j);
  float4 lb = *(const float4*)(ln_b + j);
  float4 hov, cov;
#pragma unroll
  for (int r = 0; r < 4; ++r) {
    float cn = (cv[r] - mu) * rstd * ((const float*)&lw)[r] + ((const float*)&lb)[r];
    ((float*)&cov)[r] = cn;
    ((float*)&hov)[r] = ov[r] * fast_tanh(cn);
  }
  *(float4*)(h_out + (size_t)m * H + j) = hov;
  *(float4*)(c_out + (size_t)m * H + j) = cov;
}

extern "C" void kernel_launch(void* const* d_in, const int* in_sizes, int n_in,
                              void* d_out, int out_size, void* d_ws, size_t ws_size,
                              hipStream_t stream) {
  const float* x = (const float*)d_in[0];
  const float* h = (const float*)d_in[1];
  const float* c = (const float*)d_in[2];
  const float* Wih = (const float*)d_in[3];
  const float* b_ih = (const float*)d_in[4];
  const float* Whh = (const float*)d_in[5];
  const float* b_hh = (const float*)d_in[6];
  const float* ln_w = (const float*)d_in[7];
  const float* ln_b = (const float*)d_in[8];

  char* Ai8 = (char*)d_ws;                                    // 4 MB @ 0
  char* Bi8 = (char*)d_ws + (4u << 20);                       // 8 MB @ 4M
  float* sA = (float*)((char*)d_ws + (12u << 20));            // 8 KB @ 12M
  float* sB = (float*)((char*)d_ws + (12u << 20) + 32768);    // 16 KB
  float* bsum = (float*)((char*)d_ws + (12u << 20) + 98304);  // 16 KB
  __half* cvg = (__half*)((char*)d_ws + (16u << 20));         // 4 MB @ 16M
  __half* ovg = (__half*)((char*)d_ws + (20u << 20));         // 4 MB @ 20M

  float* h_out = (float*)d_out;
  float* c_out = (float*)d_out + (size_t)BATCH * H;

  quant_kernel<<<BATCH + NDIM, 256, 0, stream>>>(x, h, Wih, Whh, b_ih, b_hh,
                                                 Ai8, Bi8, sA, sB, bsum);
  dim3 g(NDIM / BN, BATCH / BM);
  gemm_kernel<<<g, 256, 0, stream>>>(Ai8, Bi8, sA, sB, bsum, c, cvg, ovg);
  ln_kernel<<<BATCH, 256, 0, stream>>>(cvg, ovg, ln_w, ln_b, h_out, c_out);
}

// Round 17
// 46.400 us; speedup vs baseline: 1.0612x; 1.0073x over previous
//
#include <hip/hip_runtime.h>
#include <hip/hip_fp16.h>
#include <stdint.h>

#define H 1024
#define BATCH 2048
#define KDIM 2048   // input + hidden concatenated (elements)
#define NDIM 4096   // 4 gates
#define EPS 1e-5f

#define BM 128
#define BN 128   // 32 h-columns x 4 interleaved gates
#define BK 256   // i8 elements per K-step (32 KB per matrix tile)

typedef __attribute__((ext_vector_type(4))) int i32x4;

__device__ __forceinline__ float fast_sig(float x) {
  x = fminf(30.f, fmaxf(-30.f, x));
  float e = __expf(x);
  return e / (e + 1.f);
}

__device__ __forceinline__ float fast_tanh(float x) {
  x = fminf(15.f, fmaxf(-15.f, x));
  float e = __expf(2.f * x);
  return (e - 1.f) / (e + 1.f);
}

// ---- quant: per-row max-scale int8; B rows gate-interleaved (h*4+g) --------
__global__ __launch_bounds__(256) void quant_kernel(
    const float* __restrict__ x, const float* __restrict__ h,
    const float* __restrict__ Wih, const float* __restrict__ Whh,
    const float* __restrict__ b_ih, const float* __restrict__ b_hh,
    char* __restrict__ Ai8, char* __restrict__ Bi8,
    float* __restrict__ sA, float* __restrict__ sB, float* __restrict__ bsum) {
  const int r = blockIdx.x;
  const int t = threadIdx.x;
  const float* s0;
  const float* s1;
  char* dst;
  float* sOut;
  float bs = 0.f;
  float* bOut = nullptr;
  if (r < BATCH) {
    s0 = x + (size_t)r * H;
    s1 = h + (size_t)r * H;
    dst = Ai8 + (size_t)r * KDIM;
    sOut = sA + r;
  } else {
    const int rb = r - BATCH;
    const int g = rb >> 10;    // gate 0..3 (i,f,o,g)
    const int hh = rb & 1023;  // h index
    const int rr = hh * 4 + g; // interleaved row
    s0 = Wih + (size_t)rb * H;
    s1 = Whh + (size_t)rb * H;
    dst = Bi8 + (size_t)rr * KDIM;
    sOut = sB + rr;
    bs = b_ih[rb] + b_hh[rb];
    bOut = bsum + rr;
  }
  const float* src = (t < 128) ? (s0 + t * 8) : (s1 + (t - 128) * 8);
  float4 v0 = *(const float4*)src;
  float4 v1 = *(const float4*)(src + 4);
  float vv[8] = {v0.x, v0.y, v0.z, v0.w, v1.x, v1.y, v1.z, v1.w};

  float m = 0.f;
#pragma unroll
  for (int i = 0; i < 8; ++i) m = fmaxf(m, fabsf(vv[i]));
#pragma unroll
  for (int off = 32; off > 0; off >>= 1) m = fmaxf(m, __shfl_xor(m, off));
  __shared__ float red[4];
  if ((t & 63) == 0) red[t >> 6] = m;
  __syncthreads();
  m = fmaxf(fmaxf(red[0], red[1]), fmaxf(red[2], red[3]));
  m = fmaxf(m, 1e-20f);
  if (t == 0) {
    *sOut = m * (1.0f / 127.0f);
    if (bOut) *bOut = bs;
  }
  const float inv = 127.0f / m;

  char out[8];
#pragma unroll
  for (int i = 0; i < 8; ++i) {
    int qi = (int)rintf(vv[i] * inv);
    qi = max(-127, min(127, qi));
    out[i] = (char)qi;
  }
  *(int2*)(dst + t * 8) = *(const int2*)out;
}

// ---- GEMM + fused gate/c-update: int8 MFMA 16x16x64, BK=256, NT=8 ----------
__device__ __forceinline__ void load_lds16(const void* g, void* l) {
  __builtin_amdgcn_global_load_lds(
      (const __attribute__((address_space(1))) void*)g,
      (__attribute__((address_space(3))) void*)l, 16, 0, 0);
}

__global__ __launch_bounds__(256, 2) void gemm_kernel(
    const char* __restrict__ A8,   // 2048 x 2048 i8
    const char* __restrict__ B8,   // 4096 x 2048 i8 (interleaved rows)
    const float* __restrict__ sA, const float* __restrict__ sB,
    const float* __restrict__ bsum, const float* __restrict__ c_in,
    __half* __restrict__ cvg, __half* __restrict__ ovg) {  // 2048 x 1024 each
  __shared__ __align__(16) char smem[66560];  // staging 64KB | pre[128][130] f32
  char* sAt = smem;
  char* sBt = smem + 32768;
  float* pf = (float*)smem;

  const int tid = threadIdx.x;
  const int wave = tid >> 6;
  const int lane = tid & 63;
  const int m0 = blockIdx.y * BM;
  const int n0 = blockIdx.x * BN;
  const int wr = (wave >> 1) * 64;
  const int wc = (wave & 1) * 64;

  const int frow = lane & 15;
  const int klane = lane >> 4;  // 0..3
  const int rxor = (frow & 7);

  i32x4 acc[4][4] = {};

  const int NT = KDIM / BK;  // 8

  for (int t = 0; t < NT; ++t) {
    const int k0 = t * BK;
#pragma unroll
    for (int p = 0; p < 8; ++p) {
      const int rg = wave * 32 + p * 4;  // 4-row group base
      const int srcoff = (((lane & 15) ^ ((4 * (p & 1)) + (lane >> 4))) << 4);
      load_lds16(A8 + (size_t)(m0 + rg + (lane >> 4)) * KDIM + k0 + srcoff,
                 sAt + rg * BK);
      load_lds16(B8 + (size_t)(n0 + rg + (lane >> 4)) * KDIM + k0 + srcoff,
                 sBt + rg * BK);
    }
    asm volatile("s_waitcnt vmcnt(0)" ::: "memory");
    __syncthreads();

#pragma unroll
    for (int ks = 0; ks < 4; ++ks) {
      const int coff = (((ks * 4 + klane) ^ rxor) << 4);
      i32x4 a[4], b[4];
#pragma unroll
      for (int i = 0; i < 4; ++i) {
        a[i] = *(const i32x4*)(sAt + (wr + i * 16 + frow) * BK + coff);
        b[i] = *(const i32x4*)(sBt + (wc + i * 16 + frow) * BK + coff);
      }
      __builtin_amdgcn_s_setprio(1);
#pragma unroll
      for (int i = 0; i < 4; ++i)
#pragma unroll
        for (int j = 0; j < 4; ++j)
          acc[i][j] =
              __builtin_amdgcn_mfma_i32_16x16x64_i8(a[i], b[j], acc[i][j], 0, 0, 0);
      __builtin_amdgcn_s_setprio(0);
    }

    __syncthreads();
  }

  // dequant + bias -> pre-activation tile in LDS (stride 130 to spread banks)
  const int crow = (lane >> 4) << 2;
  const int ccol = lane & 15;
  float scA_[4][4], scB_[4], bs_[4];
#pragma unroll
  for (int j = 0; j < 4; ++j) {
    scB_[j] = sB[n0 + wc + j * 16 + ccol];
    bs_[j] = bsum[n0 + wc + j * 16 + ccol];
  }
#pragma unroll
  for (int i = 0; i < 4; ++i)
#pragma unroll
    for (int r = 0; r < 4; ++r) scA_[i][r] = sA[m0 + wr + i * 16 + crow + r];

#pragma unroll
  for (int i = 0; i < 4; ++i)
#pragma unroll
    for (int j = 0; j < 4; ++j) {
      const int col = wc + j * 16 + ccol;
#pragma unroll
      for (int r = 0; r < 4; ++r)
        pf[(wr + i * 16 + crow + r) * 130 + col] =
            (float)acc[i][j][r] * scA_[i][r] * scB_[j] + bs_[j];
    }
  __syncthreads();

  // fused gate math: thread -> (row = tid>>1, 16 contiguous h), coalesced IO
  const int mrow = tid >> 1;
  const int hq = tid & 1;
  const size_t obase = (size_t)(m0 + mrow) * H + blockIdx.x * 32 + hq * 16;
  const float* prow = pf + mrow * 130 + hq * 64;

  float4 cin4[4];
#pragma unroll
  for (int q = 0; q < 4; ++q) cin4[q] = *(const float4*)(c_in + obase + q * 4);

  ushort hc[16], ho[16];
#pragma unroll
  for (int k = 0; k < 16; ++k) {
    float4 g4 = *(const float4*)(prow + k * 4);  // i,f,o,g for this (m,h)
    float iv = fast_sig(g4.x);
    float fv = fast_sig(g4.y);
    float ov = fast_sig(g4.z);
    float gv = fast_tanh(g4.w);
    float cv = ((const float*)&cin4[k >> 2])[k & 3] * fv + iv * gv;
    __half hcv = __float2half(cv);
    __half hov = __float2half(ov);
    hc[k] = *(ushort*)&hcv;
    ho[k] = *(ushort*)&hov;
  }
#pragma unroll
  for (int q = 0; q < 2; ++q) {
    *(int4*)(cvg + obase + q * 8) = *(const int4*)&hc[q * 8];
    *(int4*)(ovg + obase + q * 8) = *(const int4*)&ho[q * 8];
  }
}

// ---- LN epilogue: row mean/var over cv, outputs h_t, c_t -------------------
__global__ __launch_bounds__(256) void ln_kernel(
    const __half* __restrict__ cvg, const __half* __restrict__ ovg,
    const float* __restrict__ ln_w, const float* __restrict__ ln_b,
    float* __restrict__ h_out, float* __restrict__ c_out) {
  const int m = blockIdx.x;
  const int t = threadIdx.x;
  const int j = t << 2;
  ushort4 uc = *(const ushort4*)(cvg + (size_t)m * H + j);
  ushort4 uo = *(const ushort4*)(ovg + (size_t)m * H + j);
  float cv[4] = {__half2float(*(__half*)&uc.x), __half2float(*(__half*)&uc.y),
                 __half2float(*(__half*)&uc.z), __half2float(*(__half*)&uc.w)};
  float ov[4] = {__half2float(*(__half*)&uo.x), __half2float(*(__half*)&uo.y),
                 __half2float(*(__half*)&uo.z), __half2float(*(__half*)&uo.w)};

  float s = 0.f, q = 0.f;
#pragma unroll
  for (int r = 0; r < 4; ++r) {
    s += cv[r];
    q += cv[r] * cv[r];
  }
#pragma unroll
  for (int off = 32; off > 0; off >>= 1) {
    s += __shfl_xor(s, off);
    q += __shfl_xor(q, off);
  }
  __shared__ float red[8];
  const int wv = t >> 6, ln = t & 63;
  if (ln == 0) {
    red[wv] = s;
    red[wv + 4] = q;
  }
  __syncthreads();
  s = red[0] + red[1] + red[2] + red[3];
  q = red[4] + red[5] + red[6] + red[7];
  const float mu = s * (1.f / H);
  const float var = q * (1.f / H) - mu * mu;
  const float rstd = rsqrtf(var + EPS);

  float4 lw = *(const float4*)(ln_w + j);
  float4 lb = *(const float4*)(ln_b + j);
  float4 hov, cov;
#pragma unroll
  for (int r = 0; r < 4; ++r) {
    float cn = (cv[r] - mu) * rstd * ((const float*)&lw)[r] + ((const float*)&lb)[r];
    ((float*)&cov)[r] = cn;
    ((float*)&hov)[r] = ov[r] * fast_tanh(cn);
  }
  *(float4*)(h_out + (size_t)m * H + j) = hov;
  *(float4*)(c_out + (size_t)m * H + j) = cov;
}

extern "C" void kernel_launch(void* const* d_in, const int* in_sizes, int n_in,
                              void* d_out, int out_size, void* d_ws, size_t ws_size,
                              hipStream_t stream) {
  const float* x = (const float*)d_in[0];
  const float* h = (const float*)d_in[1];
  const float* c = (const float*)d_in[2];
  const float* Wih = (const float*)d_in[3];
  const float* b_ih = (const float*)d_in[4];
  const float* Whh = (const float*)d_in[5];
  const float* b_hh = (const float*)d_in[6];
  const float* ln_w = (const float*)d_in[7];
  const float* ln_b = (const float*)d_in[8];

  char* Ai8 = (char*)d_ws;                                    // 4 MB @ 0
  char* Bi8 = (char*)d_ws + (4u << 20);                       // 8 MB @ 4M
  float* sA = (float*)((char*)d_ws + (12u << 20));            // 8 KB @ 12M
  float* sB = (float*)((char*)d_ws + (12u << 20) + 32768);    // 16 KB
  float* bsum = (float*)((char*)d_ws + (12u << 20) + 98304);  // 16 KB
  __half* cvg = (__half*)((char*)d_ws + (16u << 20));         // 4 MB @ 16M
  __half* ovg = (__half*)((char*)d_ws + (20u << 20));         // 4 MB @ 20M

  float* h_out = (float*)d_out;
  float* c_out = (float*)d_out + (size_t)BATCH * H;

  quant_kernel<<<BATCH + NDIM, 256, 0, stream>>>(x, h, Wih, Whh, b_ih, b_hh,
                                                 Ai8, Bi8, sA, sB, bsum);
  dim3 g(NDIM / BN, BATCH / BM);
  gemm_kernel<<<g, 256, 0, stream>>>(Ai8, Bi8, sA, sB, bsum, c, cvg, ovg);
  ln_kernel<<<BATCH, 256, 0, stream>>>(cvg, ovg, ln_w, ln_b, h_out, c_out);
}